// Round 1
// baseline (369.854 us; speedup 1.0000x reference)
//
#include <hip/hip_runtime.h>
#include <stdint.h>

// Problem constants (fixed by the reference)
constexpr int H_  = 2048;  // hidden
constexpr int NH_ = 16;    // heads
constexpr int HD_ = 128;   // head dim
constexpr int B_  = 2;
constexpr int T_  = 2048;
constexpr int M_  = B_ * T_;  // 4096 rows

typedef unsigned short u16;
typedef __bf16 bf16x8 __attribute__((ext_vector_type(8)));
typedef float  f32x4  __attribute__((ext_vector_type(4)));

__device__ __forceinline__ u16 f2bf(float f) {
  uint32_t u = __builtin_bit_cast(uint32_t, f);
  u += 0x7fffu + ((u >> 16) & 1u);   // round-to-nearest-even
  return (u16)(u >> 16);
}

// global -> LDS direct DMA, 16B per lane. LDS dest must be the WAVE-UNIFORM
// base (HW adds lane*16); global src is per-lane. AS3 conversion via 32-bit
// truncation (LDS aperture is 4GB-aligned; this is what LLVM's own
// addrspacecast lowering does).
__device__ __forceinline__ void gload_lds16(const void* g, void* lds) {
  auto gp = (const __attribute__((address_space(1))) uint32_t*)(uintptr_t)g;
  auto lp = (__attribute__((address_space(3))) uint32_t*)(uint32_t)(uintptr_t)lds;
  __builtin_amdgcn_global_load_lds(gp, lp, 16, 0, 0);
}

__device__ __forceinline__ f32x4 mfma16(bf16x8 a, bf16x8 b, f32x4 c) {
  return __builtin_amdgcn_mfma_f32_16x16x32_bf16(a, b, c, 0, 0, 0);
}

// ---------------------------------------------------------------- fp32->bf16
__global__ __launch_bounds__(256) void cvt_kernel(const float* __restrict__ s,
                                                  u16* __restrict__ d, int n4) {
  int i = blockIdx.x * 256 + threadIdx.x;
  if (i < n4) {
    float4 v = ((const float4*)s)[i];
    ushort4 o;
    o.x = f2bf(v.x); o.y = f2bf(v.y); o.z = f2bf(v.z); o.w = f2bf(v.w);
    ((ushort4*)d)[i] = o;
  }
}

// ------------------------------------------------------------------- GEMM BT
// C[m,n] = sum_k A[m,k]*B[n,k] + bias[n].  A:[M,K] bf16, B:[N,K] bf16.
// 128x128 tile, BK=64, 4 waves (64x64 each), double-buffered LDS,
// global_load_lds(16B) with XOR-swizzle (byte ^= ((row&7)<<4), 128B rows).
template <int OUTF32>
__global__ __launch_bounds__(256) void gemm_bt(const u16* __restrict__ A,
                                               const u16* __restrict__ Bm,
                                               const float* __restrict__ bias,
                                               void* __restrict__ Cout,
                                               int M, int N, int K) {
  __shared__ u16 As[2][128 * 64];
  __shared__ u16 Bs[2][128 * 64];
  const int tid = threadIdx.x;
  const int wave = tid >> 6, lane = tid & 63, l15 = lane & 15, lhi = lane >> 4;
  const int tm = blockIdx.x % (M >> 7), tn = blockIdx.x / (M >> 7);
  const int m0 = tm << 7, n0 = tn << 7;
  const int wr = wave >> 1, wc = wave & 1;
  const int NT = K >> 6;

  f32x4 acc[4][4] = {};

  auto stage = [&](int kt, int buf) {
#pragma unroll
    for (int is = 0; is < 4; ++is) {
      int o  = is * 4096 + tid * 16;          // linear LDS byte this lane fills
      int row = o >> 7;                        // 128B rows
      int sw  = o ^ (((o >> 7) & 7) << 4);     // involutive swizzle
      int c8  = (sw >> 4) & 7;                 // 16B slot -> k-subchunk
      gload_lds16(A + (size_t)(m0 + row) * K + kt * 64 + c8 * 8,
                  &As[buf][0] + (is * 2048 + wave * 512));
      gload_lds16(Bm + (size_t)(n0 + row) * K + kt * 64 + c8 * 8,
                  &Bs[buf][0] + (is * 2048 + wave * 512));
    }
  };

  stage(0, 0);
  __syncthreads();
  int cur = 0;
  for (int kt = 0; kt < NT; ++kt) {
    if (kt + 1 < NT) stage(kt + 1, cur ^ 1);   // async prefetch overlaps compute
#pragma unroll
    for (int kk = 0; kk < 2; ++kk) {
      bf16x8 af[4], bfr[4];
#pragma unroll
      for (int mi = 0; mi < 4; ++mi) {
        int row = wr * 64 + mi * 16 + l15;
        int ob  = (row * 128 + kk * 64 + lhi * 16) ^ ((row & 7) << 4);
        af[mi] = *(const bf16x8*)((const char*)&As[cur][0] + ob);
      }
#pragma unroll
      for (int ni = 0; ni < 4; ++ni) {
        int row = wc * 64 + ni * 16 + l15;
        int ob  = (row * 128 + kk * 64 + lhi * 16) ^ ((row & 7) << 4);
        bfr[ni] = *(const bf16x8*)((const char*)&Bs[cur][0] + ob);
      }
#pragma unroll
      for (int mi = 0; mi < 4; ++mi)
#pragma unroll
        for (int ni = 0; ni < 4; ++ni)
          acc[mi][ni] = mfma16(af[mi], bfr[ni], acc[mi][ni]);
    }
    __syncthreads();   // drains vmcnt (stage) + lgkm; next iter reads cur^1
    cur ^= 1;
  }

  float bv[4];
#pragma unroll
  for (int ni = 0; ni < 4; ++ni) bv[ni] = bias[n0 + wc * 64 + ni * 16 + l15];
#pragma unroll
  for (int mi = 0; mi < 4; ++mi) {
#pragma unroll
    for (int ni = 0; ni < 4; ++ni) {
      int n = n0 + wc * 64 + ni * 16 + l15;
#pragma unroll
      for (int r = 0; r < 4; ++r) {
        int m = m0 + wr * 64 + mi * 16 + lhi * 4 + r;  // C: row=(lane>>4)*4+reg, col=lane&15
        float v = acc[mi][ni][r] + bv[ni];
        if (OUTF32)
          ((float*)Cout)[(size_t)m * N + n] = v;
        else
          ((u16*)Cout)[(size_t)m * N + n] = f2bf(v);
      }
    }
  }
}

// ------------------------------------------------- V [B,T,H] -> Vt [B,NH,HD,T]
__global__ __launch_bounds__(256) void transpose_v(const u16* __restrict__ V,
                                                   u16* __restrict__ Vt) {
  __shared__ u16 tile[32][33];
  int bh = blockIdx.z, b = bh >> 4, h = bh & 15;
  int t0 = blockIdx.x * 32, d0 = blockIdx.y * 32;
  int x = threadIdx.x, y = threadIdx.y;  // 32 x 8
#pragma unroll
  for (int k = 0; k < 4; ++k) {
    int t = y + k * 8;
    tile[t][x] = V[(size_t)(b * T_ + t0 + t) * H_ + h * HD_ + d0 + x];
  }
  __syncthreads();
#pragma unroll
  for (int k = 0; k < 4; ++k) {
    int d = y + k * 8;
    Vt[((size_t)(bh * HD_ + d0 + d)) * T_ + t0 + x] = tile[x][d];
  }
}

// ------------------------------------------------------------ flash attention
// grid (T/64, B*NH), 4 waves x 16 q-rows. Q in regs; K,Vt staged via swizzled
// global_load_lds; online softmax with 16-lane-group shfl reductions; P via
// per-wave LDS buffer shaped for conflict-free b128 A-fragment reads.
__global__ __launch_bounds__(256) void attn_kernel(const u16* __restrict__ Q,
                                                   const u16* __restrict__ K,
                                                   const u16* __restrict__ Vt,
                                                   u16* __restrict__ ctx) {
  __shared__ u16 Ks[64 * 128];    // [key][d], 256B rows, swizzled
  __shared__ u16 Vs[128 * 64];    // [d][key], 128B rows, swizzled
  __shared__ u16 Ps[4][1024];     // per-wave P: [slot(key/8)][q][8 keys]

  const int tid = threadIdx.x, wave = tid >> 6, lane = tid & 63;
  const int l15 = lane & 15, lhi = lane >> 4;
  const int bh = blockIdx.y, b = bh >> 4, h = bh & 15;
  const int qb = blockIdx.x;
  const int q0 = qb * 64 + wave * 16;

  // Q fragments (row = lane&15, k-chunk = (lane>>4)*8) — also valid as
  // B-operand pattern; here used as A (m-side).
  bf16x8 qf[4];
  const u16* qbase = Q + (size_t)(b * T_ + q0 + l15) * H_ + h * HD_ + lhi * 8;
#pragma unroll
  for (int kk = 0; kk < 4; ++kk) qf[kk] = *(const bf16x8*)(qbase + kk * 32);

  f32x4 o[8] = {};
  float mrow[4], lrow[4];
#pragma unroll
  for (int r = 0; r < 4; ++r) { mrow[r] = -__builtin_inff(); lrow[r] = 0.f; }

  const int nkv = qb + 1;  // causal: kv blocks 0..qb
  const float scale = 0.08838834764831845f;     // 1/sqrt(128)
  const float L2E   = 1.4426950408889634f;

  for (int kvb = 0; kvb < nkv; ++kvb) {
    const int kv0 = kvb * 64;
#pragma unroll
    for (int is = 0; is < 4; ++is) {
      {  // K tile: 64 rows x 256B
        int o_ = is * 4096 + tid * 16;
        int row = o_ >> 8;
        int sw = o_ ^ (((o_ >> 8) & 7) << 4);
        int c8 = (sw >> 4) & 15;
        gload_lds16(K + (size_t)(b * T_ + kv0 + row) * H_ + h * HD_ + c8 * 8,
                    &Ks[0] + (is * 2048 + wave * 512));
      }
      {  // Vt tile: 128 rows x 128B
        int o_ = is * 4096 + tid * 16;
        int row = o_ >> 7;
        int sw = o_ ^ (((o_ >> 7) & 7) << 4);
        int t8 = (sw >> 4) & 7;
        gload_lds16(Vt + (size_t)(bh * HD_ + row) * T_ + kv0 + t8 * 8,
                    &Vs[0] + (is * 2048 + wave * 512));
      }
    }
    __syncthreads();

    // S = Q K^T (per wave: 16 q x 64 k)
    f32x4 sv[4];
#pragma unroll
    for (int kt = 0; kt < 4; ++kt) {
      f32x4 s = {0.f, 0.f, 0.f, 0.f};
#pragma unroll
      for (int kk = 0; kk < 4; ++kk) {
        int row = kt * 16 + l15;
        int ob = (row * 256 + kk * 64 + lhi * 16) ^ ((row & 7) << 4);
        bf16x8 kf = *(const bf16x8*)((const char*)&Ks[0] + ob);
        s = mfma16(qf[kk], kf, s);
      }
      sv[kt] = s;
    }

    // scale + causal mask + row max (rows = lhi*4+r, cols = l15)
    float pmax[4];
#pragma unroll
    for (int r = 0; r < 4; ++r) pmax[r] = -__builtin_inff();
#pragma unroll
    for (int kt = 0; kt < 4; ++kt) {
      int key = kv0 + kt * 16 + l15;
#pragma unroll
      for (int r = 0; r < 4; ++r) {
        int q = q0 + lhi * 4 + r;
        float xv = sv[kt][r] * scale;
        xv = (key <= q) ? xv : -__builtin_inff();
        sv[kt][r] = xv;
        pmax[r] = fmaxf(pmax[r], xv);
      }
    }
#pragma unroll
    for (int r = 0; r < 4; ++r)
#pragma unroll
      for (int d = 1; d < 16; d <<= 1)
        pmax[r] = fmaxf(pmax[r], __shfl_xor(pmax[r], d));

    float alpha[4], rsum[4];
#pragma unroll
    for (int r = 0; r < 4; ++r) {
      float mn = fmaxf(mrow[r], pmax[r]);
      alpha[r] = exp2f((mrow[r] - mn) * L2E);
      mrow[r] = mn;
      rsum[r] = 0.f;
    }
#pragma unroll
    for (int kt = 0; kt < 4; ++kt)
#pragma unroll
      for (int r = 0; r < 4; ++r) {
        float p = exp2f((sv[kt][r] - mrow[r]) * L2E);
        sv[kt][r] = p;
        rsum[r] += p;
      }
#pragma unroll
    for (int r = 0; r < 4; ++r) {
#pragma unroll
      for (int d = 1; d < 16; d <<= 1) rsum[r] += __shfl_xor(rsum[r], d);
      lrow[r] = lrow[r] * alpha[r] + rsum[r];
    }
#pragma unroll
    for (int dt = 0; dt < 8; ++dt)
#pragma unroll
      for (int r = 0; r < 4; ++r) o[dt][r] *= alpha[r];

    // P -> LDS in A-fragment-friendly layout [slot][q][8]
#pragma unroll
    for (int kt = 0; kt < 4; ++kt) {
      int keyl = kt * 16 + l15;
      int slot = keyl >> 3;
#pragma unroll
      for (int r = 0; r < 4; ++r)
        Ps[wave][slot * 128 + (lhi * 4 + r) * 8 + (keyl & 7)] = f2bf(sv[kt][r]);
    }
    asm volatile("" ::: "memory");  // order P writes before reads (same wave)

    // O += P V  (A = P[q][key], B = V[key][d] from Vt rows)
#pragma unroll
    for (int ks = 0; ks < 2; ++ks) {
      bf16x8 pf = *(const bf16x8*)&Ps[wave][(ks * 4 + lhi) * 128 + l15 * 8];
#pragma unroll
      for (int dt = 0; dt < 8; ++dt) {
        int row = dt * 16 + l15;
        int ob = (row * 128 + ks * 64 + lhi * 16) ^ ((row & 7) << 4);
        bf16x8 vf = *(const bf16x8*)((const char*)&Vs[0] + ob);
        o[dt] = mfma16(pf, vf, o[dt]);
      }
    }
    __syncthreads();   // all reads of Ks/Vs done before next stage
  }

  float inv[4];
#pragma unroll
  for (int r = 0; r < 4; ++r) inv[r] = 1.0f / lrow[r];
#pragma unroll
  for (int dt = 0; dt < 8; ++dt)
#pragma unroll
    for (int r = 0; r < 4; ++r) {
      float v = o[dt][r] * inv[r];
      ctx[(size_t)(b * T_ + q0 + lhi * 4 + r) * H_ + h * HD_ + dt * 16 + l15] =
          f2bf(v);
    }
}

// ------------------------------------------------------------------- launcher
extern "C" void kernel_launch(void* const* d_in, const int* in_sizes, int n_in,
                              void* d_out, int out_size, void* d_ws,
                              size_t ws_size, hipStream_t stream) {
  const float* x  = (const float*)d_in[0];
  const float* wq = (const float*)d_in[1];
  const float* bq = (const float*)d_in[2];
  const float* wk = (const float*)d_in[3];
  const float* bk = (const float*)d_in[4];
  const float* wv = (const float*)d_in[5];
  const float* bv = (const float*)d_in[6];
  const float* wo = (const float*)d_in[7];
  const float* bo = (const float*)d_in[8];

  // Workspace layout (needs 5*16.78MB + 4*8.39MB = 117.4 MB)
  char* ws = (char*)d_ws;
  constexpr size_t SZ_X = (size_t)M_ * H_ * 2;  // 16.8 MB (bf16 activation)
  constexpr size_t SZ_W = (size_t)H_ * H_ * 2;  // 8.4 MB (bf16 weight)
  u16* xb  = (u16*)(ws);
  u16* wqb = (u16*)(ws + SZ_X);
  u16* wkb = (u16*)(ws + SZ_X + 1 * SZ_W);
  u16* wvb = (u16*)(ws + SZ_X + 2 * SZ_W);
  u16* wob = (u16*)(ws + SZ_X + 3 * SZ_W);
  u16* Qb  = (u16*)(ws + 1 * SZ_X + 4 * SZ_W);
  u16* Kb  = (u16*)(ws + 2 * SZ_X + 4 * SZ_W);
  u16* Vb  = (u16*)(ws + 3 * SZ_X + 4 * SZ_W);
  u16* Vtb = (u16*)(ws + 4 * SZ_X + 4 * SZ_W);
  u16* ctx = xb;  // xb is dead after the QKV GEMMs; reuse for attention output

  // fp32 -> bf16 conversions
  cvt_kernel<<<(M_ * H_) / 1024, 256, 0, stream>>>(x, xb, (M_ * H_) / 4);
  cvt_kernel<<<(H_ * H_) / 1024, 256, 0, stream>>>(wq, wqb, (H_ * H_) / 4);
  cvt_kernel<<<(H_ * H_) / 1024, 256, 0, stream>>>(wk, wkb, (H_ * H_) / 4);
  cvt_kernel<<<(H_ * H_) / 1024, 256, 0, stream>>>(wv, wvb, (H_ * H_) / 4);
  cvt_kernel<<<(H_ * H_) / 1024, 256, 0, stream>>>(wo, wob, (H_ * H_) / 4);

  // QKV projections: (M/128)*(N/128) = 32*16 = 512 blocks
  gemm_bt<0><<<512, 256, 0, stream>>>(xb, wqb, bq, Qb, M_, H_, H_);
  gemm_bt<0><<<512, 256, 0, stream>>>(xb, wkb, bk, Kb, M_, H_, H_);
  gemm_bt<0><<<512, 256, 0, stream>>>(xb, wvb, bv, Vb, M_, H_, H_);

  // V -> Vt [B,NH,HD,T]
  transpose_v<<<dim3(T_ / 32, HD_ / 32, B_ * NH_), dim3(32, 8), 0, stream>>>(
      Vb, Vtb);

  // causal flash attention
  attn_kernel<<<dim3(T_ / 64, B_ * NH_), 256, 0, stream>>>(Qb, Kb, Vtb, ctx);

  // output projection, fp32 + bias to d_out
  gemm_bt<1><<<512, 256, 0, stream>>>(ctx, wob, bo, d_out, M_, H_, H_);
}

// Round 2
// 278.330 us; speedup vs baseline: 1.3288x; 1.3288x over previous
//
#include <hip/hip_runtime.h>
#include <stdint.h>

// Problem constants (fixed by the reference)
constexpr int H_  = 2048;  // hidden
constexpr int NH_ = 16;    // heads
constexpr int HD_ = 128;   // head dim
constexpr int B_  = 2;
constexpr int T_  = 2048;
constexpr int M_  = B_ * T_;  // 4096 rows

typedef unsigned short u16;
typedef __bf16 bf16x8 __attribute__((ext_vector_type(8)));
typedef float  f32x4  __attribute__((ext_vector_type(4)));

__device__ __forceinline__ u16 f2bf(float f) {
  uint32_t u = __builtin_bit_cast(uint32_t, f);
  u += 0x7fffu + ((u >> 16) & 1u);   // round-to-nearest-even
  return (u16)(u >> 16);
}

// global -> LDS direct DMA, 16B per lane. LDS dest must be the WAVE-UNIFORM
// base (HW adds lane*16); global src is per-lane.
__device__ __forceinline__ void gload_lds16(const void* g, void* lds) {
  auto gp = (const __attribute__((address_space(1))) uint32_t*)(uintptr_t)g;
  auto lp = (__attribute__((address_space(3))) uint32_t*)(uint32_t)(uintptr_t)lds;
  __builtin_amdgcn_global_load_lds(gp, lp, 16, 0, 0);
}

__device__ __forceinline__ f32x4 mfma16(bf16x8 a, bf16x8 b, f32x4 c) {
  return __builtin_amdgcn_mfma_f32_16x16x32_bf16(a, b, c, 0, 0, 0);
}

// ---------------------------------------------------------------- fp32->bf16
__global__ __launch_bounds__(256) void cvt_kernel(const float* __restrict__ s,
                                                  u16* __restrict__ d, int n4) {
  int i = blockIdx.x * 256 + threadIdx.x;
  if (i < n4) {
    float4 v = ((const float4*)s)[i];
    ushort4 o;
    o.x = f2bf(v.x); o.y = f2bf(v.y); o.z = f2bf(v.z); o.w = f2bf(v.w);
    ((ushort4*)d)[i] = o;
  }
}

// ------------------------------------------------------------------- GEMM BT
// C[m,n] = sum_k A[m,k]*B[n,k] + bias[n].  A:[M,K] bf16, B:[N,K] bf16.
// 128x128 tile, BK=64, 4 waves (64x64 each), double-buffered LDS,
// global_load_lds(16B) with XOR-swizzle (byte ^= ((row&7)<<4), 128B rows).
template <int OUTF32>
__global__ __launch_bounds__(256) void gemm_bt(const u16* __restrict__ A,
                                               const u16* __restrict__ Bm,
                                               const float* __restrict__ bias,
                                               void* __restrict__ Cout,
                                               int M, int N, int K) {
  __shared__ u16 As[2][128 * 64];
  __shared__ u16 Bs[2][128 * 64];
  const int tid = threadIdx.x;
  const int wave = tid >> 6, lane = tid & 63, l15 = lane & 15, lhi = lane >> 4;
  const int tm = blockIdx.x % (M >> 7), tn = blockIdx.x / (M >> 7);
  const int m0 = tm << 7, n0 = tn << 7;
  const int wr = wave >> 1, wc = wave & 1;
  const int NT = K >> 6;

  f32x4 acc[4][4] = {};

  auto stage = [&](int kt, int buf) {
#pragma unroll
    for (int is = 0; is < 4; ++is) {
      int o  = is * 4096 + tid * 16;          // linear LDS byte this lane fills
      int row = o >> 7;                        // 128B rows
      int sw  = o ^ (((o >> 7) & 7) << 4);     // involutive swizzle
      int c8  = (sw >> 4) & 7;                 // 16B slot -> k-subchunk
      gload_lds16(A + (size_t)(m0 + row) * K + kt * 64 + c8 * 8,
                  &As[buf][0] + (is * 2048 + wave * 512));
      gload_lds16(Bm + (size_t)(n0 + row) * K + kt * 64 + c8 * 8,
                  &Bs[buf][0] + (is * 2048 + wave * 512));
    }
  };

  stage(0, 0);
  __syncthreads();
  int cur = 0;
  for (int kt = 0; kt < NT; ++kt) {
    if (kt + 1 < NT) stage(kt + 1, cur ^ 1);   // async prefetch overlaps compute
#pragma unroll
    for (int kk = 0; kk < 2; ++kk) {
      bf16x8 af[4], bfr[4];
#pragma unroll
      for (int mi = 0; mi < 4; ++mi) {
        int row = wr * 64 + mi * 16 + l15;
        int ob  = (row * 128 + kk * 64 + lhi * 16) ^ ((row & 7) << 4);
        af[mi] = *(const bf16x8*)((const char*)&As[cur][0] + ob);
      }
#pragma unroll
      for (int ni = 0; ni < 4; ++ni) {
        int row = wc * 64 + ni * 16 + l15;
        int ob  = (row * 128 + kk * 64 + lhi * 16) ^ ((row & 7) << 4);
        bfr[ni] = *(const bf16x8*)((const char*)&Bs[cur][0] + ob);
      }
#pragma unroll
      for (int mi = 0; mi < 4; ++mi)
#pragma unroll
        for (int ni = 0; ni < 4; ++ni)
          acc[mi][ni] = mfma16(af[mi], bfr[ni], acc[mi][ni]);
    }
    __syncthreads();
    cur ^= 1;
  }

  float bv[4];
#pragma unroll
  for (int ni = 0; ni < 4; ++ni) bv[ni] = bias[n0 + wc * 64 + ni * 16 + l15];
#pragma unroll
  for (int mi = 0; mi < 4; ++mi) {
#pragma unroll
    for (int ni = 0; ni < 4; ++ni) {
      int n = n0 + wc * 64 + ni * 16 + l15;
#pragma unroll
      for (int r = 0; r < 4; ++r) {
        int m = m0 + wr * 64 + mi * 16 + lhi * 4 + r;
        float v = acc[mi][ni][r] + bv[ni];
        if (OUTF32)
          ((float*)Cout)[(size_t)m * N + n] = v;
        else
          ((u16*)Cout)[(size_t)m * N + n] = f2bf(v);
      }
    }
  }
}

// ------------------------------------------------- V [B,T,H] -> Vt [B,NH,HD,T]
__global__ __launch_bounds__(256) void transpose_v(const u16* __restrict__ V,
                                                   u16* __restrict__ Vt) {
  __shared__ u16 tile[32][33];
  int bh = blockIdx.z, b = bh >> 4, h = bh & 15;
  int t0 = blockIdx.x * 32, d0 = blockIdx.y * 32;
  int x = threadIdx.x, y = threadIdx.y;  // 32 x 8
#pragma unroll
  for (int k = 0; k < 4; ++k) {
    int t = y + k * 8;
    tile[t][x] = V[(size_t)(b * T_ + t0 + t) * H_ + h * HD_ + d0 + x];
  }
  __syncthreads();
#pragma unroll
  for (int k = 0; k < 4; ++k) {
    int d = y + k * 8;
    Vt[((size_t)(bh * HD_ + d0 + d)) * T_ + t0 + x] = tile[x][d];
  }
}

// ------------------------------------------------------------ flash attention
// v2: work-balanced q-tile PAIRING (block handles q-tiles i and 31-i -> every
// block does exactly 33 KV iterations; 512 blocks = 2/CU, no tail), K/V
// double-buffered via global_load_lds prefetch, diag-only masking, T13
// defer-max (skip O rescale unless row max grew > 8 nats), log2-domain
// softmax with scale folded into one FMA.
__global__ __launch_bounds__(256) void attn_kernel(const u16* __restrict__ Q,
                                                   const u16* __restrict__ K,
                                                   const u16* __restrict__ Vt,
                                                   u16* __restrict__ ctx) {
  __shared__ u16 Ks[2][64 * 128];    // [key][d], 256B rows, swizzled
  __shared__ u16 Vs[2][128 * 64];    // [d][key], 128B rows, swizzled
  __shared__ u16 Ps[4][1024];        // per-wave P: [slot(key/8)][q][8 keys]

  const int tid = threadIdx.x, wave = tid >> 6, lane = tid & 63;
  const int l15 = lane & 15, lhi = lane >> 4;
  const int bh = blockIdx.y, b = bh >> 4, h = bh & 15;
  const int nQB = T_ / 64;                       // 32
  const int qbs[2] = {(int)blockIdx.x, nQB - 1 - (int)blockIdx.x};

  const float C1  = 0.08838834764831845f * 1.4426950408889634f;  // scale*log2e
  const float THR = 11.5f;                       // 8 nats in log2 units

  auto stage = [&](int buf, int kv0) {
#pragma unroll
    for (int is = 0; is < 4; ++is) {
      {  // K tile: 64 rows x 256B
        int o_ = is * 4096 + tid * 16;
        int row = o_ >> 8;
        int sw = o_ ^ (((o_ >> 8) & 7) << 4);
        int c8 = (sw >> 4) & 15;
        gload_lds16(K + (size_t)(b * T_ + kv0 + row) * H_ + h * HD_ + c8 * 8,
                    &Ks[buf][0] + (is * 2048 + wave * 512));
      }
      {  // Vt tile: 128 rows x 128B
        int o_ = is * 4096 + tid * 16;
        int row = o_ >> 7;
        int sw = o_ ^ (((o_ >> 7) & 7) << 4);
        int t8 = (sw >> 4) & 7;
        gload_lds16(Vt + (size_t)(bh * HD_ + row) * T_ + kv0 + t8 * 8,
                    &Vs[buf][0] + (is * 2048 + wave * 512));
      }
    }
  };

  stage(0, 0);
  __syncthreads();
  int cur = 0;

  for (int s = 0; s < 2; ++s) {
    const int qb = qbs[s];
    const int q0 = qb * 64 + wave * 16;

    // Q fragments (row = lane&15, k-chunk = (lane>>4)*8)
    bf16x8 qf[4];
    const u16* qbase = Q + (size_t)(b * T_ + q0 + l15) * H_ + h * HD_ + lhi * 8;
#pragma unroll
    for (int kk = 0; kk < 4; ++kk) qf[kk] = *(const bf16x8*)(qbase + kk * 32);

    f32x4 o[8] = {};
    float m2[4], lr[4];
#pragma unroll
    for (int r = 0; r < 4; ++r) { m2[r] = -__builtin_inff(); lr[r] = 0.f; }

    for (int kvb = 0; kvb <= qb; ++kvb) {
      const int kv0 = kvb * 64;

      // prefetch next tile (next kv, or segment 1's kv=0)
      const bool has_next = (kvb < qb) || (s == 0);
      if (has_next) stage(cur ^ 1, (kvb < qb) ? (kvb + 1) * 64 : 0);

      // S = Q K^T (per wave: 16 q x 64 k)
      f32x4 sv[4];
#pragma unroll
      for (int kt = 0; kt < 4; ++kt) {
        f32x4 sacc = {0.f, 0.f, 0.f, 0.f};
#pragma unroll
        for (int kk = 0; kk < 4; ++kk) {
          int row = kt * 16 + l15;
          int ob = (row * 256 + kk * 64 + lhi * 16) ^ ((row & 7) << 4);
          bf16x8 kf = *(const bf16x8*)((const char*)&Ks[cur][0] + ob);
          sacc = mfma16(qf[kk], kf, sacc);
        }
        sv[kt] = sacc;
      }

      // log2-domain scores; mask only on the diagonal block
      float pmax2[4];
#pragma unroll
      for (int r = 0; r < 4; ++r) pmax2[r] = -__builtin_inff();
      if (kvb == qb) {
#pragma unroll
        for (int kt = 0; kt < 4; ++kt) {
          int key = kv0 + kt * 16 + l15;
#pragma unroll
          for (int r = 0; r < 4; ++r) {
            int q = q0 + lhi * 4 + r;
            float z = sv[kt][r] * C1;
            z = (key <= q) ? z : -__builtin_inff();
            sv[kt][r] = z;
            pmax2[r] = fmaxf(pmax2[r], z);
          }
        }
      } else {
#pragma unroll
        for (int kt = 0; kt < 4; ++kt)
#pragma unroll
          for (int r = 0; r < 4; ++r) {
            float z = sv[kt][r] * C1;
            sv[kt][r] = z;
            pmax2[r] = fmaxf(pmax2[r], z);
          }
      }
#pragma unroll
      for (int r = 0; r < 4; ++r)
#pragma unroll
        for (int d = 1; d < 16; d <<= 1)
          pmax2[r] = fmaxf(pmax2[r], __shfl_xor(pmax2[r], d));

      // T13 defer-max: only rescale when some row grew past threshold
      bool need = false;
#pragma unroll
      for (int r = 0; r < 4; ++r) need |= (pmax2[r] - m2[r] > THR);
      if (__any(need)) {
#pragma unroll
        for (int r = 0; r < 4; ++r) {
          float mn = fmaxf(m2[r], pmax2[r]);
          float al = exp2f(m2[r] - mn);
          m2[r] = mn;
          lr[r] *= al;
#pragma unroll
          for (int dt = 0; dt < 8; ++dt) o[dt][r] *= al;
        }
      }

      float rs[4] = {0.f, 0.f, 0.f, 0.f};
#pragma unroll
      for (int kt = 0; kt < 4; ++kt)
#pragma unroll
        for (int r = 0; r < 4; ++r) {
          float p = exp2f(sv[kt][r] - m2[r]);
          sv[kt][r] = p;
          rs[r] += p;
        }
#pragma unroll
      for (int r = 0; r < 4; ++r) {
#pragma unroll
        for (int d = 1; d < 16; d <<= 1) rs[r] += __shfl_xor(rs[r], d);
        lr[r] += rs[r];
      }

      // P -> LDS in A-fragment-friendly layout [slot][q][8]
#pragma unroll
      for (int kt = 0; kt < 4; ++kt) {
        int keyl = kt * 16 + l15;
        int slot = keyl >> 3;
#pragma unroll
        for (int r = 0; r < 4; ++r)
          Ps[wave][slot * 128 + (lhi * 4 + r) * 8 + (keyl & 7)] =
              f2bf(sv[kt][r]);
      }
      asm volatile("" ::: "memory");

      // O += P V  (A = P[q][key], B = V[key][d] from Vt rows)
#pragma unroll
      for (int ks = 0; ks < 2; ++ks) {
        bf16x8 pf = *(const bf16x8*)&Ps[wave][(ks * 4 + lhi) * 128 + l15 * 8];
#pragma unroll
        for (int dt = 0; dt < 8; ++dt) {
          int row = dt * 16 + l15;
          int ob = (row * 128 + ks * 64 + lhi * 16) ^ ((row & 7) << 4);
          bf16x8 vf = *(const bf16x8*)((const char*)&Vs[cur][0] + ob);
          o[dt] = mfma16(pf, vf, o[dt]);
        }
      }
      __syncthreads();   // drains prefetch vmcnt + guards buffer reuse
      cur ^= 1;
    }

    float inv[4];
#pragma unroll
    for (int r = 0; r < 4; ++r) inv[r] = 1.0f / lr[r];
#pragma unroll
    for (int dt = 0; dt < 8; ++dt)
#pragma unroll
      for (int r = 0; r < 4; ++r) {
        float v = o[dt][r] * inv[r];
        ctx[(size_t)(b * T_ + q0 + lhi * 4 + r) * H_ + h * HD_ + dt * 16 +
            l15] = f2bf(v);
      }
  }
}

// ------------------------------------------------------------------- launcher
extern "C" void kernel_launch(void* const* d_in, const int* in_sizes, int n_in,
                              void* d_out, int out_size, void* d_ws,
                              size_t ws_size, hipStream_t stream) {
  const float* x  = (const float*)d_in[0];
  const float* wq = (const float*)d_in[1];
  const float* bq = (const float*)d_in[2];
  const float* wk = (const float*)d_in[3];
  const float* bk = (const float*)d_in[4];
  const float* wv = (const float*)d_in[5];
  const float* bv = (const float*)d_in[6];
  const float* wo = (const float*)d_in[7];
  const float* bo = (const float*)d_in[8];

  char* ws = (char*)d_ws;
  constexpr size_t SZ_X = (size_t)M_ * H_ * 2;  // 16.8 MB (bf16 activation)
  constexpr size_t SZ_W = (size_t)H_ * H_ * 2;  // 8.4 MB (bf16 weight)
  u16* xb  = (u16*)(ws);
  u16* wqb = (u16*)(ws + SZ_X);
  u16* wkb = (u16*)(ws + SZ_X + 1 * SZ_W);
  u16* wvb = (u16*)(ws + SZ_X + 2 * SZ_W);
  u16* wob = (u16*)(ws + SZ_X + 3 * SZ_W);
  u16* Qb  = (u16*)(ws + 1 * SZ_X + 4 * SZ_W);
  u16* Kb  = (u16*)(ws + 2 * SZ_X + 4 * SZ_W);
  u16* Vb  = (u16*)(ws + 3 * SZ_X + 4 * SZ_W);
  u16* Vtb = (u16*)(ws + 4 * SZ_X + 4 * SZ_W);
  u16* ctx = xb;  // xb is dead after the QKV GEMMs

  cvt_kernel<<<(M_ * H_) / 1024, 256, 0, stream>>>(x, xb, (M_ * H_) / 4);
  cvt_kernel<<<(H_ * H_) / 1024, 256, 0, stream>>>(wq, wqb, (H_ * H_) / 4);
  cvt_kernel<<<(H_ * H_) / 1024, 256, 0, stream>>>(wk, wkb, (H_ * H_) / 4);
  cvt_kernel<<<(H_ * H_) / 1024, 256, 0, stream>>>(wv, wvb, (H_ * H_) / 4);
  cvt_kernel<<<(H_ * H_) / 1024, 256, 0, stream>>>(wo, wob, (H_ * H_) / 4);

  gemm_bt<0><<<512, 256, 0, stream>>>(xb, wqb, bq, Qb, M_, H_, H_);
  gemm_bt<0><<<512, 256, 0, stream>>>(xb, wkb, bk, Kb, M_, H_, H_);
  gemm_bt<0><<<512, 256, 0, stream>>>(xb, wvb, bv, Vb, M_, H_, H_);

  transpose_v<<<dim3(T_ / 32, HD_ / 32, B_ * NH_), dim3(32, 8), 0, stream>>>(
      Vb, Vtb);

  // paired causal flash attention: grid.x = (T/64)/2 = 16
  attn_kernel<<<dim3(T_ / 128, B_ * NH_), 256, 0, stream>>>(Qb, Kb, Vtb, ctx);

  gemm_bt<1><<<512, 256, 0, stream>>>(ctx, wob, bo, d_out, M_, H_, H_);
}

// Round 3
// 256.909 us; speedup vs baseline: 1.4396x; 1.0834x over previous
//
#include <hip/hip_runtime.h>
#include <stdint.h>

// Problem constants (fixed by the reference)
constexpr int H_  = 2048;  // hidden
constexpr int NH_ = 16;    // heads
constexpr int HD_ = 128;   // head dim
constexpr int B_  = 2;
constexpr int T_  = 2048;
constexpr int M_  = B_ * T_;  // 4096 rows

typedef unsigned short u16;
typedef __bf16 bf16x8 __attribute__((ext_vector_type(8)));
typedef float  f32x4  __attribute__((ext_vector_type(4)));

__device__ __forceinline__ u16 f2bf(float f) {
  uint32_t u = __builtin_bit_cast(uint32_t, f);
  u += 0x7fffu + ((u >> 16) & 1u);   // round-to-nearest-even
  return (u16)(u >> 16);
}

// global -> LDS direct DMA, 16B per lane. LDS dest must be the WAVE-UNIFORM
// base (HW adds lane*16); global src is per-lane.
__device__ __forceinline__ void gload_lds16(const void* g, void* lds) {
  auto gp = (const __attribute__((address_space(1))) uint32_t*)(uintptr_t)g;
  auto lp = (__attribute__((address_space(3))) uint32_t*)(uint32_t)(uintptr_t)lds;
  __builtin_amdgcn_global_load_lds(gp, lp, 16, 0, 0);
}

__device__ __forceinline__ f32x4 mfma16(bf16x8 a, bf16x8 b, f32x4 c) {
  return __builtin_amdgcn_mfma_f32_16x16x32_bf16(a, b, c, 0, 0, 0);
}

// ---------------------------------------------------------------- fp32->bf16
__global__ __launch_bounds__(256) void cvt_kernel(const float* __restrict__ s,
                                                  u16* __restrict__ d, int n4) {
  int i = blockIdx.x * 256 + threadIdx.x;
  if (i < n4) {
    float4 v = ((const float4*)s)[i];
    ushort4 o;
    o.x = f2bf(v.x); o.y = f2bf(v.y); o.z = f2bf(v.z); o.w = f2bf(v.w);
    ((ushort4*)d)[i] = o;
  }
}

// ------------------------------------------------------------------- GEMM BT
// (unchanged from round 2 — ~1000 TF each, at this structure's ceiling)
template <int OUTF32>
__global__ __launch_bounds__(256) void gemm_bt(const u16* __restrict__ A,
                                               const u16* __restrict__ Bm,
                                               const float* __restrict__ bias,
                                               void* __restrict__ Cout,
                                               int M, int N, int K) {
  __shared__ u16 As[2][128 * 64];
  __shared__ u16 Bs[2][128 * 64];
  const int tid = threadIdx.x;
  const int wave = tid >> 6, lane = tid & 63, l15 = lane & 15, lhi = lane >> 4;
  const int tm = blockIdx.x % (M >> 7), tn = blockIdx.x / (M >> 7);
  const int m0 = tm << 7, n0 = tn << 7;
  const int wr = wave >> 1, wc = wave & 1;
  const int NT = K >> 6;

  f32x4 acc[4][4] = {};

  auto stage = [&](int kt, int buf) {
#pragma unroll
    for (int is = 0; is < 4; ++is) {
      int o  = is * 4096 + tid * 16;
      int row = o >> 7;
      int sw  = o ^ (((o >> 7) & 7) << 4);
      int c8  = (sw >> 4) & 7;
      gload_lds16(A + (size_t)(m0 + row) * K + kt * 64 + c8 * 8,
                  &As[buf][0] + (is * 2048 + wave * 512));
      gload_lds16(Bm + (size_t)(n0 + row) * K + kt * 64 + c8 * 8,
                  &Bs[buf][0] + (is * 2048 + wave * 512));
    }
  };

  stage(0, 0);
  __syncthreads();
  int cur = 0;
  for (int kt = 0; kt < NT; ++kt) {
    if (kt + 1 < NT) stage(kt + 1, cur ^ 1);
#pragma unroll
    for (int kk = 0; kk < 2; ++kk) {
      bf16x8 af[4], bfr[4];
#pragma unroll
      for (int mi = 0; mi < 4; ++mi) {
        int row = wr * 64 + mi * 16 + l15;
        int ob  = (row * 128 + kk * 64 + lhi * 16) ^ ((row & 7) << 4);
        af[mi] = *(const bf16x8*)((const char*)&As[cur][0] + ob);
      }
#pragma unroll
      for (int ni = 0; ni < 4; ++ni) {
        int row = wc * 64 + ni * 16 + l15;
        int ob  = (row * 128 + kk * 64 + lhi * 16) ^ ((row & 7) << 4);
        bfr[ni] = *(const bf16x8*)((const char*)&Bs[cur][0] + ob);
      }
#pragma unroll
      for (int mi = 0; mi < 4; ++mi)
#pragma unroll
        for (int ni = 0; ni < 4; ++ni)
          acc[mi][ni] = mfma16(af[mi], bfr[ni], acc[mi][ni]);
    }
    __syncthreads();
    cur ^= 1;
  }

  float bv[4];
#pragma unroll
  for (int ni = 0; ni < 4; ++ni) bv[ni] = bias[n0 + wc * 64 + ni * 16 + l15];
#pragma unroll
  for (int mi = 0; mi < 4; ++mi) {
#pragma unroll
    for (int ni = 0; ni < 4; ++ni) {
      int n = n0 + wc * 64 + ni * 16 + l15;
#pragma unroll
      for (int r = 0; r < 4; ++r) {
        int m = m0 + wr * 64 + mi * 16 + lhi * 4 + r;
        float v = acc[mi][ni][r] + bv[ni];
        if (OUTF32)
          ((float*)Cout)[(size_t)m * N + n] = v;
        else
          ((u16*)Cout)[(size_t)m * N + n] = f2bf(v);
      }
    }
  }
}

// ------------------------------------------------- V [B,T,H] -> Vt [B,NH,HD,T]
__global__ __launch_bounds__(256) void transpose_v(const u16* __restrict__ V,
                                                   u16* __restrict__ Vt) {
  __shared__ u16 tile[32][33];
  int bh = blockIdx.z, b = bh >> 4, h = bh & 15;
  int t0 = blockIdx.x * 32, d0 = blockIdx.y * 32;
  int x = threadIdx.x, y = threadIdx.y;  // 32 x 8
#pragma unroll
  for (int k = 0; k < 4; ++k) {
    int t = y + k * 8;
    tile[t][x] = V[(size_t)(b * T_ + t0 + t) * H_ + h * HD_ + d0 + x];
  }
  __syncthreads();
#pragma unroll
  for (int k = 0; k < 4; ++k) {
    int d = y + k * 8;
    Vt[((size_t)(bh * HD_ + d0 + d)) * T_ + t0 + x] = tile[x][d];
  }
}

// ------------------------------------------------------------ flash attention
// v3 changes vs v2:
//  * counted-vmcnt 2-barrier schedule: stage(t+1); vmcnt(8); barrier; compute;
//    barrier  -> prefetch never drained to 0 in the main loop (T3/T4).
//  * swapped QK^T: S^T = mfma(K,Q) -> per-lane q-column (q=l15), row stats are
//    lane-local; only 2 shfl_xor steps (16,32) per reduce; m,l are scalars.
//  * Ps XOR-swizzled + packed ds_write_b64 (conflict-free b128 reads).
//  * XCD-grouped 1D grid: XCD x serves bh in [4x,4x+4) -> 4MB KV set fits L2.
//  * s_setprio(1) around MFMA clusters (T5).
__global__ __launch_bounds__(256) void attn_kernel(const u16* __restrict__ Q,
                                                   const u16* __restrict__ K,
                                                   const u16* __restrict__ Vt,
                                                   u16* __restrict__ ctx) {
  __shared__ u16 Ks[2][64 * 128];    // [key][d], 256B rows, swizzled
  __shared__ u16 Vs[2][128 * 64];    // [d][key], 128B rows, swizzled
  __shared__ u16 Ps[4][1024];        // per-wave P^T, swizzled [slot][q][8]

  const int tid = threadIdx.x, wave = tid >> 6, lane = tid & 63;
  const int l15 = lane & 15, lhi = lane >> 4;

  // XCD-grouped decode (512 blocks; dispatch round-robins bid%8 across XCDs)
  const int bid = blockIdx.x;
  const int xcd = bid & 7, idx = bid >> 3;
  const int bh = xcd * 4 + (idx & 3);     // 4 (b,h) pairs per XCD
  const int qi = idx >> 2;                // 0..15
  const int b = bh >> 4, h = bh & 15;
  const int nQB = T_ / 64;                // 32
  const int qbs[2] = {qi, nQB - 1 - qi};  // balanced pair: 33 iters total

  const float C1  = 0.08838834764831845f * 1.4426950408889634f;  // scale*log2e
  const float THR = 11.5f;                // 8 nats in log2 units
  const float NI  = -__builtin_inff();

  auto stage = [&](int buf, int kv0) {
#pragma unroll
    for (int is = 0; is < 4; ++is) {
      {  // K tile: 64 rows x 256B
        int o_ = is * 4096 + tid * 16;
        int row = o_ >> 8;
        int sw = o_ ^ (((o_ >> 8) & 7) << 4);
        int c8 = (sw >> 4) & 15;
        gload_lds16(K + (size_t)(b * T_ + kv0 + row) * H_ + h * HD_ + c8 * 8,
                    &Ks[buf][0] + (is * 2048 + wave * 512));
      }
      {  // Vt tile: 128 rows x 128B
        int o_ = is * 4096 + tid * 16;
        int row = o_ >> 7;
        int sw = o_ ^ (((o_ >> 7) & 7) << 4);
        int t8 = (sw >> 4) & 7;
        gload_lds16(Vt + (size_t)(bh * HD_ + row) * T_ + kv0 + t8 * 8,
                    &Vs[buf][0] + (is * 2048 + wave * 512));
      }
    }
  };

  stage(0, 0);
  asm volatile("s_waitcnt vmcnt(0)" ::: "memory");
  __builtin_amdgcn_s_barrier();
  asm volatile("" ::: "memory");
  int cur = 0;

  for (int s = 0; s < 2; ++s) {
    const int qb = qbs[s];
    const int q0 = qb * 64 + wave * 16;
    const int qrow = q0 + l15;            // this lane's q (S^T domain)

    bf16x8 qf[4];
    const u16* qbase = Q + (size_t)(b * T_ + q0 + l15) * H_ + h * HD_ + lhi * 8;
#pragma unroll
    for (int kk = 0; kk < 4; ++kk) qf[kk] = *(const bf16x8*)(qbase + kk * 32);

    f32x4 o[8] = {};
    float m2 = NI, lr = 0.f;

    for (int kvb = 0; kvb <= qb; ++kvb) {
      const int kv0 = kvb * 64;
      const bool has_next = (kvb < qb) || (s == 0);
      if (has_next) {
        stage(cur ^ 1, (kvb < qb) ? kv0 + 64 : 0);
        asm volatile("s_waitcnt vmcnt(8)" ::: "memory");  // cur's loads done
      } else {
        asm volatile("s_waitcnt vmcnt(0)" ::: "memory");
      }
      __builtin_amdgcn_s_barrier();       // publish cur tile
      asm volatile("" ::: "memory");

      // S^T = K Q^T: lane holds keys {kt*16+lhi*4+r}, q = l15
      f32x4 sv[4];
      __builtin_amdgcn_s_setprio(1);
#pragma unroll
      for (int kt = 0; kt < 4; ++kt) {
        f32x4 sacc = {0.f, 0.f, 0.f, 0.f};
#pragma unroll
        for (int kk = 0; kk < 4; ++kk) {
          int row = kt * 16 + l15;
          int ob = (row * 256 + kk * 64 + lhi * 16) ^ ((row & 7) << 4);
          bf16x8 kf = *(const bf16x8*)((const char*)&Ks[cur][0] + ob);
          sacc = mfma16(kf, qf[kk], sacc);
        }
        sv[kt] = sacc;
      }
      __builtin_amdgcn_s_setprio(0);

      float pmax2 = NI;
      if (kvb == qb) {  // diagonal: causal mask
#pragma unroll
        for (int kt = 0; kt < 4; ++kt)
#pragma unroll
          for (int r = 0; r < 4; ++r) {
            int key = kv0 + kt * 16 + lhi * 4 + r;
            float z = sv[kt][r] * C1;
            z = (key <= qrow) ? z : NI;
            sv[kt][r] = z;
            pmax2 = fmaxf(pmax2, z);
          }
      } else {
#pragma unroll
        for (int kt = 0; kt < 4; ++kt)
#pragma unroll
          for (int r = 0; r < 4; ++r) {
            float z = sv[kt][r] * C1;
            sv[kt][r] = z;
            pmax2 = fmaxf(pmax2, z);
          }
      }
      pmax2 = fmaxf(pmax2, __shfl_xor(pmax2, 16));
      pmax2 = fmaxf(pmax2, __shfl_xor(pmax2, 32));

      // T13 defer-max
      if (__any(pmax2 - m2 > THR)) {
        float mn = fmaxf(m2, pmax2);
        float al = exp2f(m2 - mn);
        m2 = mn;
        lr *= al;
        float alo[4];
#pragma unroll
        for (int r = 0; r < 4; ++r) alo[r] = __shfl(al, lhi * 4 + r);
#pragma unroll
        for (int dt = 0; dt < 8; ++dt)
#pragma unroll
          for (int r = 0; r < 4; ++r) o[dt][r] *= alo[r];
      }

      float rs = 0.f;
#pragma unroll
      for (int kt = 0; kt < 4; ++kt)
#pragma unroll
        for (int r = 0; r < 4; ++r) {
          float p = exp2f(sv[kt][r] - m2);
          sv[kt][r] = p;
          rs += p;
        }
      rs += __shfl_xor(rs, 16);
      rs += __shfl_xor(rs, 32);
      lr += rs;

      // P^T -> Ps: one b64 per kt; swizzled, conflict-free on read
#pragma unroll
      for (int kt = 0; kt < 4; ++kt) {
        int slot = kt * 2 + (lhi >> 1);
        ushort4 pk;
        pk.x = f2bf(sv[kt][0]);
        pk.y = f2bf(sv[kt][1]);
        pk.z = f2bf(sv[kt][2]);
        pk.w = f2bf(sv[kt][3]);
        *(ushort4*)&Ps[wave][slot * 128 + ((l15 * 8) ^ ((slot & 7) << 3)) +
                             (lhi & 1) * 4] = pk;
      }
      asm volatile("" ::: "memory");

      // O += P V
      __builtin_amdgcn_s_setprio(1);
#pragma unroll
      for (int ks = 0; ks < 2; ++ks) {
        int slot = ks * 4 + lhi;
        bf16x8 pf = *(const bf16x8*)&Ps[wave][slot * 128 +
                                              ((l15 * 8) ^ ((slot & 7) << 3))];
#pragma unroll
        for (int dt = 0; dt < 8; ++dt) {
          int row = dt * 16 + l15;
          int ob = (row * 128 + ks * 64 + lhi * 16) ^ ((row & 7) << 4);
          bf16x8 vf = *(const bf16x8*)((const char*)&Vs[cur][0] + ob);
          o[dt] = mfma16(pf, vf, o[dt]);
        }
      }
      __builtin_amdgcn_s_setprio(0);

      __builtin_amdgcn_s_barrier();   // release cur before next stage
      asm volatile("" ::: "memory");
      cur ^= 1;
    }

    float invo[4];
    {
      float inv = 1.0f / lr;
#pragma unroll
      for (int r = 0; r < 4; ++r) invo[r] = __shfl(inv, lhi * 4 + r);
    }
#pragma unroll
    for (int dt = 0; dt < 8; ++dt)
#pragma unroll
      for (int r = 0; r < 4; ++r) {
        float v = o[dt][r] * invo[r];
        ctx[(size_t)(b * T_ + q0 + lhi * 4 + r) * H_ + h * HD_ + dt * 16 +
            l15] = f2bf(v);
      }
  }
}

// ------------------------------------------------------------------- launcher
extern "C" void kernel_launch(void* const* d_in, const int* in_sizes, int n_in,
                              void* d_out, int out_size, void* d_ws,
                              size_t ws_size, hipStream_t stream) {
  const float* x  = (const float*)d_in[0];
  const float* wq = (const float*)d_in[1];
  const float* bq = (const float*)d_in[2];
  const float* wk = (const float*)d_in[3];
  const float* bk = (const float*)d_in[4];
  const float* wv = (const float*)d_in[5];
  const float* bv = (const float*)d_in[6];
  const float* wo = (const float*)d_in[7];
  const float* bo = (const float*)d_in[8];

  char* ws = (char*)d_ws;
  constexpr size_t SZ_X = (size_t)M_ * H_ * 2;  // 16.8 MB (bf16 activation)
  constexpr size_t SZ_W = (size_t)H_ * H_ * 2;  // 8.4 MB (bf16 weight)
  u16* xb  = (u16*)(ws);
  u16* wqb = (u16*)(ws + SZ_X);
  u16* wkb = (u16*)(ws + SZ_X + 1 * SZ_W);
  u16* wvb = (u16*)(ws + SZ_X + 2 * SZ_W);
  u16* wob = (u16*)(ws + SZ_X + 3 * SZ_W);
  u16* Qb  = (u16*)(ws + 1 * SZ_X + 4 * SZ_W);
  u16* Kb  = (u16*)(ws + 2 * SZ_X + 4 * SZ_W);
  u16* Vb  = (u16*)(ws + 3 * SZ_X + 4 * SZ_W);
  u16* Vtb = (u16*)(ws + 4 * SZ_X + 4 * SZ_W);
  u16* ctx = xb;  // xb is dead after the QKV GEMMs

  cvt_kernel<<<(M_ * H_) / 1024, 256, 0, stream>>>(x, xb, (M_ * H_) / 4);
  cvt_kernel<<<(H_ * H_) / 1024, 256, 0, stream>>>(wq, wqb, (H_ * H_) / 4);
  cvt_kernel<<<(H_ * H_) / 1024, 256, 0, stream>>>(wk, wkb, (H_ * H_) / 4);
  cvt_kernel<<<(H_ * H_) / 1024, 256, 0, stream>>>(wv, wvb, (H_ * H_) / 4);
  cvt_kernel<<<(H_ * H_) / 1024, 256, 0, stream>>>(wo, wob, (H_ * H_) / 4);

  gemm_bt<0><<<512, 256, 0, stream>>>(xb, wqb, bq, Qb, M_, H_, H_);
  gemm_bt<0><<<512, 256, 0, stream>>>(xb, wkb, bk, Kb, M_, H_, H_);
  gemm_bt<0><<<512, 256, 0, stream>>>(xb, wvb, bv, Vb, M_, H_, H_);

  transpose_v<<<dim3(T_ / 32, HD_ / 32, B_ * NH_), dim3(32, 8), 0, stream>>>(
      Vb, Vtb);

  // XCD-grouped paired causal flash attention: 512 blocks, 1D
  attn_kernel<<<512, 256, 0, stream>>>(Qb, Kb, Vtb, ctx);

  gemm_bt<1><<<512, 256, 0, stream>>>(ctx, wob, bo, d_out, M_, H_, H_);
}

// Round 4
// 243.377 us; speedup vs baseline: 1.5197x; 1.0556x over previous
//
#include <hip/hip_runtime.h>
#include <stdint.h>

// Problem constants (fixed by the reference)
constexpr int H_  = 2048;  // hidden
constexpr int NH_ = 16;    // heads
constexpr int HD_ = 128;   // head dim
constexpr int B_  = 2;
constexpr int T_  = 2048;
constexpr int M_  = B_ * T_;  // 4096 rows

typedef unsigned short u16;
typedef __bf16 bf16x8 __attribute__((ext_vector_type(8)));
typedef float  f32x4  __attribute__((ext_vector_type(4)));

__device__ __forceinline__ u16 f2bf(float f) {
  uint32_t u = __builtin_bit_cast(uint32_t, f);
  u += 0x7fffu + ((u >> 16) & 1u);   // round-to-nearest-even
  return (u16)(u >> 16);
}

// global -> LDS direct DMA, 16B per lane. LDS dest must be the WAVE-UNIFORM
// base (HW adds lane*16); global src is per-lane.
__device__ __forceinline__ void gload_lds16(const void* g, void* lds) {
  auto gp = (const __attribute__((address_space(1))) uint32_t*)(uintptr_t)g;
  auto lp = (__attribute__((address_space(3))) uint32_t*)(uint32_t)(uintptr_t)lds;
  __builtin_amdgcn_global_load_lds(gp, lp, 16, 0, 0);
}

__device__ __forceinline__ f32x4 mfma16(bf16x8 a, bf16x8 b, f32x4 c) {
  return __builtin_amdgcn_mfma_f32_16x16x32_bf16(a, b, c, 0, 0, 0);
}

// ------------------------------------------------------- fused fp32->bf16 x5
// Block-range partition over {x, wq, wk, wv, wo}; dst regions are contiguous
// in ws in exactly this order. All ranges exact (no bounds checks).
__global__ __launch_bounds__(512) void cvt5_kernel(
    const float4* __restrict__ x,  const float4* __restrict__ wq,
    const float4* __restrict__ wk, const float4* __restrict__ wv,
    const float4* __restrict__ wo, ushort4* __restrict__ dst) {
  const int bid = blockIdx.x, tid = threadIdx.x;
  const float4* src;
  size_t idx, dof;
  if (bid < 4096) {                         // x: 2,097,152 float4
    src = x; idx = (size_t)bid * 512 + tid; dof = 0;
  } else {                                  // weights: 1,048,576 float4 each
    int w = (bid - 4096) >> 11;
    int r = (bid - 4096) & 2047;
    idx = (size_t)r * 512 + tid;
    dof = 2097152u + (size_t)w * 1048576u;
    src = (w == 0) ? wq : (w == 1) ? wk : (w == 2) ? wv : wo;
  }
  float4 v = src[idx];
  ushort4 o;
  o.x = f2bf(v.x); o.y = f2bf(v.y); o.z = f2bf(v.z); o.w = f2bf(v.w);
  dst[dof + idx] = o;
}

// ------------------------------------------------------------------- GEMM BT
// C[m,n] = sum_k A[m,k]*B[n,k] + bias[n].  A:[M,K] bf16, B:[N,K] bf16.
// 128x128 tile, BK=64, 4 waves, double-buffered LDS, global_load_lds(16B),
// XOR-swizzle, and (v4) counted-vmcnt 2-barrier schedule: the prefetch for
// tile t+1 stays in flight across the publish barrier (vmcnt(8), never 0
// mid-loop).  OUTMODE: 0 = bf16 [M,N], 1 = f32 [M,N], 2 = bf16 V^T -> Vt.
template <int OUTMODE>
__global__ __launch_bounds__(256) void gemm_bt(const u16* __restrict__ A,
                                               const u16* __restrict__ Bm,
                                               const float* __restrict__ bias,
                                               void* __restrict__ Cout,
                                               int M, int N, int K) {
  __shared__ u16 As[2][128 * 64];
  __shared__ u16 Bs[2][128 * 64];
  const int tid = threadIdx.x;
  const int wave = tid >> 6, lane = tid & 63, l15 = lane & 15, lhi = lane >> 4;
  const int tm = blockIdx.x % (M >> 7), tn = blockIdx.x / (M >> 7);
  const int m0 = tm << 7, n0 = tn << 7;
  const int wr = wave >> 1, wc = wave & 1;
  const int NT = K >> 6;

  f32x4 acc[4][4] = {};

  auto stage = [&](int kt, int buf) {
#pragma unroll
    for (int is = 0; is < 4; ++is) {
      int o  = is * 4096 + tid * 16;
      int row = o >> 7;
      int sw  = o ^ (((o >> 7) & 7) << 4);
      int c8  = (sw >> 4) & 7;
      gload_lds16(A + (size_t)(m0 + row) * K + kt * 64 + c8 * 8,
                  &As[buf][0] + (is * 2048 + wave * 512));
      gload_lds16(Bm + (size_t)(n0 + row) * K + kt * 64 + c8 * 8,
                  &Bs[buf][0] + (is * 2048 + wave * 512));
    }
  };

  stage(0, 0);
  int cur = 0;
  for (int kt = 0; kt < NT; ++kt) {
    if (kt + 1 < NT) {
      stage(kt + 1, cur ^ 1);                          // 8 loads -> buf^1
      asm volatile("s_waitcnt vmcnt(8)" ::: "memory"); // tile kt's loads done
    } else {
      asm volatile("s_waitcnt vmcnt(0)" ::: "memory");
    }
    __builtin_amdgcn_s_barrier();                      // publish tile kt
    asm volatile("" ::: "memory");
#pragma unroll
    for (int kk = 0; kk < 2; ++kk) {
      bf16x8 af[4], bfr[4];
#pragma unroll
      for (int mi = 0; mi < 4; ++mi) {
        int row = wr * 64 + mi * 16 + l15;
        int ob  = (row * 128 + kk * 64 + lhi * 16) ^ ((row & 7) << 4);
        af[mi] = *(const bf16x8*)((const char*)&As[cur][0] + ob);
      }
#pragma unroll
      for (int ni = 0; ni < 4; ++ni) {
        int row = wc * 64 + ni * 16 + l15;
        int ob  = (row * 128 + kk * 64 + lhi * 16) ^ ((row & 7) << 4);
        bfr[ni] = *(const bf16x8*)((const char*)&Bs[cur][0] + ob);
      }
#pragma unroll
      for (int mi = 0; mi < 4; ++mi)
#pragma unroll
        for (int ni = 0; ni < 4; ++ni)
          acc[mi][ni] = mfma16(af[mi], bfr[ni], acc[mi][ni]);
    }
    __builtin_amdgcn_s_barrier();   // release cur before next stage overwrite
    asm volatile("" ::: "memory");
    cur ^= 1;
  }

  float bv[4];
#pragma unroll
  for (int ni = 0; ni < 4; ++ni) bv[ni] = bias[n0 + wc * 64 + ni * 16 + l15];

  if constexpr (OUTMODE == 2) {
    // V^T epilogue: element (m,n) -> Vt[(b*2048 + n) * T + t], b=m>>11,
    // t=m&2047.  4 r-values are t-contiguous -> one ushort4 store per frag.
    const int b = m0 >> 11;                 // constant per block (m-range 128)
    const int tbase = (m0 & 2047) + wr * 64 + lhi * 4;
#pragma unroll
    for (int mi = 0; mi < 4; ++mi) {
#pragma unroll
      for (int ni = 0; ni < 4; ++ni) {
        int n = n0 + wc * 64 + ni * 16 + l15;
        ushort4 pk;
        pk.x = f2bf(acc[mi][ni][0] + bv[ni]);
        pk.y = f2bf(acc[mi][ni][1] + bv[ni]);
        pk.z = f2bf(acc[mi][ni][2] + bv[ni]);
        pk.w = f2bf(acc[mi][ni][3] + bv[ni]);
        *(ushort4*)((u16*)Cout + (size_t)(b * 2048 + n) * T_ + tbase +
                    mi * 16) = pk;
      }
    }
  } else {
#pragma unroll
    for (int mi = 0; mi < 4; ++mi) {
#pragma unroll
      for (int ni = 0; ni < 4; ++ni) {
        int n = n0 + wc * 64 + ni * 16 + l15;
#pragma unroll
        for (int r = 0; r < 4; ++r) {
          int m = m0 + wr * 64 + mi * 16 + lhi * 4 + r;
          float v = acc[mi][ni][r] + bv[ni];
          if (OUTMODE == 1)
            ((float*)Cout)[(size_t)m * N + n] = v;
          else
            ((u16*)Cout)[(size_t)m * N + n] = f2bf(v);
        }
      }
    }
  }
}

// ------------------------------------------------------------ flash attention
// (unchanged from round 3)
__global__ __launch_bounds__(256) void attn_kernel(const u16* __restrict__ Q,
                                                   const u16* __restrict__ K,
                                                   const u16* __restrict__ Vt,
                                                   u16* __restrict__ ctx) {
  __shared__ u16 Ks[2][64 * 128];    // [key][d], 256B rows, swizzled
  __shared__ u16 Vs[2][128 * 64];    // [d][key], 128B rows, swizzled
  __shared__ u16 Ps[4][1024];        // per-wave P^T, swizzled [slot][q][8]

  const int tid = threadIdx.x, wave = tid >> 6, lane = tid & 63;
  const int l15 = lane & 15, lhi = lane >> 4;

  const int bid = blockIdx.x;
  const int xcd = bid & 7, idx = bid >> 3;
  const int bh = xcd * 4 + (idx & 3);     // 4 (b,h) pairs per XCD
  const int qi = idx >> 2;                // 0..15
  const int b = bh >> 4, h = bh & 15;
  const int nQB = T_ / 64;                // 32
  const int qbs[2] = {qi, nQB - 1 - qi};  // balanced pair: 33 iters total

  const float C1  = 0.08838834764831845f * 1.4426950408889634f;  // scale*log2e
  const float THR = 11.5f;                // 8 nats in log2 units
  const float NI  = -__builtin_inff();

  auto stage = [&](int buf, int kv0) {
#pragma unroll
    for (int is = 0; is < 4; ++is) {
      {  // K tile: 64 rows x 256B
        int o_ = is * 4096 + tid * 16;
        int row = o_ >> 8;
        int sw = o_ ^ (((o_ >> 8) & 7) << 4);
        int c8 = (sw >> 4) & 15;
        gload_lds16(K + (size_t)(b * T_ + kv0 + row) * H_ + h * HD_ + c8 * 8,
                    &Ks[buf][0] + (is * 2048 + wave * 512));
      }
      {  // Vt tile: 128 rows x 128B
        int o_ = is * 4096 + tid * 16;
        int row = o_ >> 7;
        int sw = o_ ^ (((o_ >> 7) & 7) << 4);
        int t8 = (sw >> 4) & 7;
        gload_lds16(Vt + (size_t)(bh * HD_ + row) * T_ + kv0 + t8 * 8,
                    &Vs[buf][0] + (is * 2048 + wave * 512));
      }
    }
  };

  stage(0, 0);
  asm volatile("s_waitcnt vmcnt(0)" ::: "memory");
  __builtin_amdgcn_s_barrier();
  asm volatile("" ::: "memory");
  int cur = 0;

  for (int s = 0; s < 2; ++s) {
    const int qb = qbs[s];
    const int q0 = qb * 64 + wave * 16;
    const int qrow = q0 + l15;            // this lane's q (S^T domain)

    bf16x8 qf[4];
    const u16* qbase = Q + (size_t)(b * T_ + q0 + l15) * H_ + h * HD_ + lhi * 8;
#pragma unroll
    for (int kk = 0; kk < 4; ++kk) qf[kk] = *(const bf16x8*)(qbase + kk * 32);

    f32x4 o[8] = {};
    float m2 = NI, lr = 0.f;

    for (int kvb = 0; kvb <= qb; ++kvb) {
      const int kv0 = kvb * 64;
      const bool has_next = (kvb < qb) || (s == 0);
      if (has_next) {
        stage(cur ^ 1, (kvb < qb) ? kv0 + 64 : 0);
        asm volatile("s_waitcnt vmcnt(8)" ::: "memory");  // cur's loads done
      } else {
        asm volatile("s_waitcnt vmcnt(0)" ::: "memory");
      }
      __builtin_amdgcn_s_barrier();       // publish cur tile
      asm volatile("" ::: "memory");

      // S^T = K Q^T: lane holds keys {kt*16+lhi*4+r}, q = l15
      f32x4 sv[4];
      __builtin_amdgcn_s_setprio(1);
#pragma unroll
      for (int kt = 0; kt < 4; ++kt) {
        f32x4 sacc = {0.f, 0.f, 0.f, 0.f};
#pragma unroll
        for (int kk = 0; kk < 4; ++kk) {
          int row = kt * 16 + l15;
          int ob = (row * 256 + kk * 64 + lhi * 16) ^ ((row & 7) << 4);
          bf16x8 kf = *(const bf16x8*)((const char*)&Ks[cur][0] + ob);
          sacc = mfma16(kf, qf[kk], sacc);
        }
        sv[kt] = sacc;
      }
      __builtin_amdgcn_s_setprio(0);

      float pmax2 = NI;
      if (kvb == qb) {  // diagonal: causal mask
#pragma unroll
        for (int kt = 0; kt < 4; ++kt)
#pragma unroll
          for (int r = 0; r < 4; ++r) {
            int key = kv0 + kt * 16 + lhi * 4 + r;
            float z = sv[kt][r] * C1;
            z = (key <= qrow) ? z : NI;
            sv[kt][r] = z;
            pmax2 = fmaxf(pmax2, z);
          }
      } else {
#pragma unroll
        for (int kt = 0; kt < 4; ++kt)
#pragma unroll
          for (int r = 0; r < 4; ++r) {
            float z = sv[kt][r] * C1;
            sv[kt][r] = z;
            pmax2 = fmaxf(pmax2, z);
          }
      }
      pmax2 = fmaxf(pmax2, __shfl_xor(pmax2, 16));
      pmax2 = fmaxf(pmax2, __shfl_xor(pmax2, 32));

      // T13 defer-max
      if (__any(pmax2 - m2 > THR)) {
        float mn = fmaxf(m2, pmax2);
        float al = exp2f(m2 - mn);
        m2 = mn;
        lr *= al;
        float alo[4];
#pragma unroll
        for (int r = 0; r < 4; ++r) alo[r] = __shfl(al, lhi * 4 + r);
#pragma unroll
        for (int dt = 0; dt < 8; ++dt)
#pragma unroll
          for (int r = 0; r < 4; ++r) o[dt][r] *= alo[r];
      }

      float rs = 0.f;
#pragma unroll
      for (int kt = 0; kt < 4; ++kt)
#pragma unroll
        for (int r = 0; r < 4; ++r) {
          float p = exp2f(sv[kt][r] - m2);
          sv[kt][r] = p;
          rs += p;
        }
      rs += __shfl_xor(rs, 16);
      rs += __shfl_xor(rs, 32);
      lr += rs;

      // P^T -> Ps: one b64 per kt; swizzled, conflict-free on read
#pragma unroll
      for (int kt = 0; kt < 4; ++kt) {
        int slot = kt * 2 + (lhi >> 1);
        ushort4 pk;
        pk.x = f2bf(sv[kt][0]);
        pk.y = f2bf(sv[kt][1]);
        pk.z = f2bf(sv[kt][2]);
        pk.w = f2bf(sv[kt][3]);
        *(ushort4*)&Ps[wave][slot * 128 + ((l15 * 8) ^ ((slot & 7) << 3)) +
                             (lhi & 1) * 4] = pk;
      }
      asm volatile("" ::: "memory");

      // O += P V
      __builtin_amdgcn_s_setprio(1);
#pragma unroll
      for (int ks = 0; ks < 2; ++ks) {
        int slot = ks * 4 + lhi;
        bf16x8 pf = *(const bf16x8*)&Ps[wave][slot * 128 +
                                              ((l15 * 8) ^ ((slot & 7) << 3))];
#pragma unroll
        for (int dt = 0; dt < 8; ++dt) {
          int row = dt * 16 + l15;
          int ob = (row * 128 + ks * 64 + lhi * 16) ^ ((row & 7) << 4);
          bf16x8 vf = *(const bf16x8*)((const char*)&Vs[cur][0] + ob);
          o[dt] = mfma16(pf, vf, o[dt]);
        }
      }
      __builtin_amdgcn_s_setprio(0);

      __builtin_amdgcn_s_barrier();   // release cur before next stage
      asm volatile("" ::: "memory");
      cur ^= 1;
    }

    float invo[4];
    {
      float inv = 1.0f / lr;
#pragma unroll
      for (int r = 0; r < 4; ++r) invo[r] = __shfl(inv, lhi * 4 + r);
    }
#pragma unroll
    for (int dt = 0; dt < 8; ++dt)
#pragma unroll
      for (int r = 0; r < 4; ++r) {
        float v = o[dt][r] * invo[r];
        ctx[(size_t)(b * T_ + q0 + lhi * 4 + r) * H_ + h * HD_ + dt * 16 +
            l15] = f2bf(v);
      }
  }
}

// ------------------------------------------------------------------- launcher
extern "C" void kernel_launch(void* const* d_in, const int* in_sizes, int n_in,
                              void* d_out, int out_size, void* d_ws,
                              size_t ws_size, hipStream_t stream) {
  const float* x  = (const float*)d_in[0];
  const float* wq = (const float*)d_in[1];
  const float* bq = (const float*)d_in[2];
  const float* wk = (const float*)d_in[3];
  const float* bk = (const float*)d_in[4];
  const float* wv = (const float*)d_in[5];
  const float* bv = (const float*)d_in[6];
  const float* wo = (const float*)d_in[7];
  const float* bo = (const float*)d_in[8];

  char* ws = (char*)d_ws;
  constexpr size_t SZ_X = (size_t)M_ * H_ * 2;  // 16.8 MB (bf16 activation)
  constexpr size_t SZ_W = (size_t)H_ * H_ * 2;  // 8.4 MB (bf16 weight)
  u16* xb  = (u16*)(ws);
  u16* wqb = (u16*)(ws + SZ_X);
  u16* wkb = (u16*)(ws + SZ_X + 1 * SZ_W);
  u16* wvb = (u16*)(ws + SZ_X + 2 * SZ_W);
  u16* wob = (u16*)(ws + SZ_X + 3 * SZ_W);
  u16* Qb  = (u16*)(ws + 1 * SZ_X + 4 * SZ_W);
  u16* Kb  = (u16*)(ws + 2 * SZ_X + 4 * SZ_W);
  u16* Vtb = (u16*)(ws + 3 * SZ_X + 4 * SZ_W);  // V^T written by gemm_bt<2>
  u16* ctx = xb;  // xb is dead after the QKV GEMMs

  // fused fp32->bf16: x + 4 weights, one dispatch (dsts contiguous in ws)
  cvt5_kernel<<<12288, 512, 0, stream>>>((const float4*)x, (const float4*)wq,
                                         (const float4*)wk, (const float4*)wv,
                                         (const float4*)wo, (ushort4*)ws);

  gemm_bt<0><<<512, 256, 0, stream>>>(xb, wqb, bq, Qb, M_, H_, H_);
  gemm_bt<0><<<512, 256, 0, stream>>>(xb, wkb, bk, Kb, M_, H_, H_);
  gemm_bt<2><<<512, 256, 0, stream>>>(xb, wvb, bv, Vtb, M_, H_, H_);

  // XCD-grouped paired causal flash attention: 512 blocks, 1D
  attn_kernel<<<512, 256, 0, stream>>>(Qb, Kb, Vtb, ctx);

  gemm_bt<1><<<512, 256, 0, stream>>>(ctx, wob, bo, d_out, M_, H_, H_);
}